// Round 5
// baseline (261.543 us; speedup 1.0000x reference)
//
#include <hip/hip_runtime.h>

#define NBLOCKS 2048
#define NTHREADS 256
#define ITERS 16
// R11: discriminating MLP test. R10 proved launch structure is irrelevant
// (one-shot 72us == persistent 73us) and R9 proved NT > cached (72 vs 101).
// R3's FETCH~0 replays at 101us prove we are NOT BW-bound (even L3-resident
// reads cap at ~2.7-3.7 TB/s) -> suspect per-CU outstanding-load
// concurrency. This round: FULL unroll, all 32 NT loads (16 pred4 +
// 16 lab4) issued per thread before any compute (~128 VGPR buffered).
// Occupancy halves but per-wave in-flight loads go 8 -> 32.
// If unchanged: per-CU concurrency is a HW cap -> roofline.
// Numerics unchanged from passing kernels: per-4-elem f32 sum -> f64 acc.

typedef float fvec4 __attribute__((ext_vector_type(4)));
typedef int   ivec4 __attribute__((ext_vector_type(4)));
typedef double dvec2 __attribute__((ext_vector_type(2)));

__device__ __forceinline__ fvec4 ntloadf(const fvec4* p) {
    return __builtin_nontemporal_load(p);
}
__device__ __forceinline__ ivec4 ntloadi(const ivec4* p) {
    return __builtin_nontemporal_load(p);
}

__global__ __launch_bounds__(NTHREADS) void wmse_kernel(
    const fvec4* __restrict__ pred4,
    const ivec4* __restrict__ lab4,
    const float* __restrict__ weights,
    double* __restrict__ partials,
    int n4)
{
    __shared__ float w[16];

    const int S = NBLOCKS * NTHREADS;            // 2^19 float4 groups
    const int t = blockIdx.x * NTHREADS + threadIdx.x;

    double acc = 0.0;

    if (n4 == S * ITERS) {
        // ---- issue ALL 32 streaming loads before any compute/barrier ----
        fvec4 p[ITERS];
        ivec4 l[ITERS];
        #pragma unroll
        for (int k = 0; k < ITERS; ++k) {
            p[k] = ntloadf(pred4 + t + k * S);
            l[k] = ntloadi(lab4 + t + k * S);
        }

        if (threadIdx.x < 10) w[threadIdx.x] = weights[threadIdx.x];
        __syncthreads();

        // ---- compute: same per-group numerics as the passing kernels ----
        #pragma unroll
        for (int k = 0; k < ITERS; ++k) {
            float d0 = p[k].x - (float)l[k].x, d1 = p[k].y - (float)l[k].y;
            float d2 = p[k].z - (float)l[k].z, d3 = p[k].w - (float)l[k].w;
            float s = w[l[k].x]*d0*d0 + w[l[k].y]*d1*d1
                    + w[l[k].z]*d2*d2 + w[l[k].w]*d3*d3;
            acc += (double)s;
        }
    } else {
        // generic fallback (not taken for N = 2^25)
        if (threadIdx.x < 10) w[threadIdx.x] = weights[threadIdx.x];
        __syncthreads();
        for (int i = t; i < n4; i += S) {
            fvec4 p = pred4[i];
            ivec4 l = lab4[i];
            float d0 = p.x - (float)l.x, d1 = p.y - (float)l.y;
            float d2 = p.z - (float)l.z, d3 = p.w - (float)l.w;
            acc += (double)(w[l.x]*d0*d0 + w[l.y]*d1*d1
                          + w[l.z]*d2*d2 + w[l.w]*d3*d3);
        }
    }

    // 64-lane wave shuffle reduction (f64)
    for (int off = 32; off > 0; off >>= 1)
        acc += __shfl_down(acc, off, 64);

    __shared__ double wave_sums[NTHREADS / 64];
    int lane = threadIdx.x & 63;
    int wid  = threadIdx.x >> 6;
    if (lane == 0) wave_sums[wid] = acc;
    __syncthreads();

    if (threadIdx.x == 0) {
        double tsum = 0.0;
        #pragma unroll
        for (int k = 0; k < NTHREADS / 64; ++k) tsum += wave_sums[k];
        partials[blockIdx.x] = tsum;
    }
}

#define FTHREADS 1024

__global__ __launch_bounds__(FTHREADS) void wmse_final_kernel(
    const dvec2* __restrict__ partials2,   // NBLOCKS/2 double2s
    float* __restrict__ out,
    double inv_n)
{
    // NBLOCKS/2 = 1024 double2; 1024 threads -> 1 vector load each
    double acc = 0.0;
    #pragma unroll
    for (int k = 0; k < NBLOCKS / 2 / FTHREADS; ++k) {
        dvec2 v = partials2[threadIdx.x + k * FTHREADS];
        acc += v.x + v.y;
    }

    for (int off = 32; off > 0; off >>= 1)
        acc += __shfl_down(acc, off, 64);

    __shared__ double wave_sums[FTHREADS / 64];
    int lane = threadIdx.x & 63;
    int wid  = threadIdx.x >> 6;
    if (lane == 0) wave_sums[wid] = acc;
    __syncthreads();

    if (threadIdx.x == 0) {
        double t = 0.0;
        #pragma unroll
        for (int k = 0; k < FTHREADS / 64; ++k) t += wave_sums[k];
        out[0] = (float)(t * inv_n);
    }
}

extern "C" void kernel_launch(void* const* d_in, const int* in_sizes, int n_in,
                              void* d_out, int out_size, void* d_ws, size_t ws_size,
                              hipStream_t stream) {
    const float* pred    = (const float*)d_in[0];
    const int*   labels  = (const int*)d_in[1];
    const float* weights = (const float*)d_in[2];
    float* out = (float*)d_out;

    int n  = in_sizes[0];          // 33,554,432 = 2^25
    int n4 = n >> 2;

    double* partials = (double*)d_ws;   // 2048 doubles = 16 KB

    wmse_kernel<<<NBLOCKS, NTHREADS, 0, stream>>>(
        (const fvec4*)pred, (const ivec4*)labels, weights, partials, n4);

    wmse_final_kernel<<<1, FTHREADS, 0, stream>>>(
        (const dvec2*)partials, out, 1.0 / (double)n);
}

// Round 6
// 252.904 us; speedup vs baseline: 1.0342x; 1.0342x over previous
//
#include <hip/hip_runtime.h>

#define NBLOCKS 2048
#define NTHREADS 256
#define WAVES (NTHREADS / 64)    // 4 waves/block
#define CHUNKS 16
// R12: probe the global_load_lds (direct-to-LDS DMA) read path.
// Established: NT one-shot 72us == NT persistent 73us (launch structure
// null, R10); full-unroll MLP null (R11); cached loads +29us (R9,
// dirty-L3 writeback). Effective pure-read BW stuck at 3.7 TB/s while
// fills write at 6.9 -> theory: per-CU TCP outstanding-miss cap
// (~64 lines x ~600ns = ~3.6 TB/s chip-wide) on the VGPR-return path.
// global_load_lds has a different return path (no VGPR round-trip);
// each wave stages 1KB pred + 1KB lab chunks into wave-PRIVATE LDS
// double buffers, counted vmcnt(2) pipeline, NO barriers in the loop.
// aux=2 = NT bit (gfx940+ CPol) to keep the proven no-allocate policy.

typedef float fvec4 __attribute__((ext_vector_type(4)));
typedef int   ivec4 __attribute__((ext_vector_type(4)));
typedef double dvec2 __attribute__((ext_vector_type(2)));

typedef const __attribute__((address_space(1))) unsigned int guint;
typedef __attribute__((address_space(3))) unsigned int luint;

__device__ __forceinline__ void stage16(const void* gptr, void* ldsptr) {
    // one global_load_lds_dwordx4: 64 lanes x 16B -> 1KB, LDS dest =
    // wave-uniform base + lane*16 (HW rule), global src per-lane.
    __builtin_amdgcn_global_load_lds((guint*)gptr, (luint*)ldsptr, 16, 0, 2 /*NT*/);
}

__global__ __launch_bounds__(NTHREADS) void wmse_kernel(
    const fvec4* __restrict__ pred4,
    const ivec4* __restrict__ lab4,
    const float* __restrict__ weights,
    double* __restrict__ partials,
    int n4)
{
    __shared__ float w[16];
    __shared__ fvec4 lds_p[2][WAVES][64];   // 8 KB
    __shared__ ivec4 lds_l[2][WAVES][64];   // 8 KB

    if (threadIdx.x < 10) w[threadIdx.x] = weights[threadIdx.x];
    __syncthreads();   // weights ready; staging below is wave-private

    const int lane = threadIdx.x & 63;
    const int wid  = threadIdx.x >> 6;
    const int S = NBLOCKS * NTHREADS;        // 2^19 float4 groups / chunk
    const int t = blockIdx.x * NTHREADS + threadIdx.x;

    double acc = 0.0;

    if (n4 == S * CHUNKS) {
        // prologue: stage chunk 0 into buf 0
        stage16(pred4 + t, &lds_p[0][wid][0]);
        stage16(lab4  + t, &lds_l[0][wid][0]);

        #pragma unroll
        for (int k = 0; k < CHUNKS; ++k) {
            const int cur = k & 1;
            if (k + 1 < CHUNKS) {
                const int nxt = (k + 1) & 1;
                const int idx = t + (k + 1) * S;
                stage16(pred4 + idx, &lds_p[nxt][wid][0]);
                stage16(lab4  + idx, &lds_l[nxt][wid][0]);
                // 4 outstanding stages; wait until only next-chunk's 2 remain
                asm volatile("s_waitcnt vmcnt(2)" ::: "memory");
            } else {
                asm volatile("s_waitcnt vmcnt(0)" ::: "memory");
            }
            fvec4 p = lds_p[cur][wid][lane];
            ivec4 l = lds_l[cur][wid][lane];
            float d0 = p.x - (float)l.x, d1 = p.y - (float)l.y;
            float d2 = p.z - (float)l.z, d3 = p.w - (float)l.w;
            float s = w[l.x]*d0*d0 + w[l.y]*d1*d1
                    + w[l.z]*d2*d2 + w[l.w]*d3*d3;
            acc += (double)s;
        }
    } else {
        // generic fallback (not taken for N = 2^25)
        for (int i = t; i < n4; i += S) {
            fvec4 p = pred4[i];
            ivec4 l = lab4[i];
            float d0 = p.x - (float)l.x, d1 = p.y - (float)l.y;
            float d2 = p.z - (float)l.z, d3 = p.w - (float)l.w;
            acc += (double)(w[l.x]*d0*d0 + w[l.y]*d1*d1
                          + w[l.z]*d2*d2 + w[l.w]*d3*d3);
        }
    }

    // 64-lane wave shuffle reduction (f64)
    for (int off = 32; off > 0; off >>= 1)
        acc += __shfl_down(acc, off, 64);

    __shared__ double wave_sums[WAVES];
    if (lane == 0) wave_sums[wid] = acc;
    __syncthreads();

    if (threadIdx.x == 0) {
        double tsum = 0.0;
        #pragma unroll
        for (int k = 0; k < WAVES; ++k) tsum += wave_sums[k];
        partials[blockIdx.x] = tsum;
    }
}

#define FTHREADS 1024

__global__ __launch_bounds__(FTHREADS) void wmse_final_kernel(
    const dvec2* __restrict__ partials2,   // NBLOCKS/2 double2s
    float* __restrict__ out,
    double inv_n)
{
    // NBLOCKS/2 = 1024 double2; 1024 threads -> 1 vector load each
    double acc = 0.0;
    #pragma unroll
    for (int k = 0; k < NBLOCKS / 2 / FTHREADS; ++k) {
        dvec2 v = partials2[threadIdx.x + k * FTHREADS];
        acc += v.x + v.y;
    }

    for (int off = 32; off > 0; off >>= 1)
        acc += __shfl_down(acc, off, 64);

    __shared__ double wave_sums[FTHREADS / 64];
    int lane = threadIdx.x & 63;
    int wid  = threadIdx.x >> 6;
    if (lane == 0) wave_sums[wid] = acc;
    __syncthreads();

    if (threadIdx.x == 0) {
        double t = 0.0;
        #pragma unroll
        for (int k = 0; k < FTHREADS / 64; ++k) t += wave_sums[k];
        out[0] = (float)(t * inv_n);
    }
}

extern "C" void kernel_launch(void* const* d_in, const int* in_sizes, int n_in,
                              void* d_out, int out_size, void* d_ws, size_t ws_size,
                              hipStream_t stream) {
    const float* pred    = (const float*)d_in[0];
    const int*   labels  = (const int*)d_in[1];
    const float* weights = (const float*)d_in[2];
    float* out = (float*)d_out;

    int n  = in_sizes[0];          // 33,554,432 = 2^25
    int n4 = n >> 2;

    double* partials = (double*)d_ws;   // 2048 doubles = 16 KB

    wmse_kernel<<<NBLOCKS, NTHREADS, 0, stream>>>(
        (const fvec4*)pred, (const ivec4*)labels, weights, partials, n4);

    wmse_final_kernel<<<1, FTHREADS, 0, stream>>>(
        (const dvec2*)partials, out, 1.0 / (double)n);
}